// Round 7
// baseline (1024.267 us; speedup 1.0000x reference)
//
#include <hip/hip_runtime.h>

#define N_NODES 100000
#define N_EDGES 500000
#define N_GRAPHS 100
#define DIM 146
#define APAD 160        // padded bf16 row stride (16B-aligned, 5 k-chunks of 32)
#define BN_EPS 1e-5f
#define GS_PART 8
#define GS_STRIDE 147   // 146 cols + 1 count slot
#define ST_PART 4       // stat-atomic partitions

typedef __bf16 bf16x8 __attribute__((ext_vector_type(8)));
typedef float floatx4 __attribute__((ext_vector_type(4)));
typedef unsigned short ushort_t;
typedef unsigned int uint_t;

__device__ inline ushort_t f2bf(float x) {
  uint_t u = __float_as_uint(x);
  uint_t r = (u + 0x7fffu + ((u >> 16) & 1u)) >> 16;   // RNE
  return (ushort_t)r;
}
__device__ inline float bf2f(ushort_t b) { return __uint_as_float((uint_t)b << 16); }
__device__ inline uint_t pack2bf(float a, float b) {
  return (uint_t)f2bf(a) | ((uint_t)f2bf(b) << 16);
}
__device__ inline float bflo(uint_t u) { return __uint_as_float(u << 16); }
__device__ inline float bfhi(uint_t u) { return __uint_as_float(u & 0xffff0000u); }

// async global->LDS, 16 B per lane (global_load_lds_dwordx4)
__device__ inline void async_cp16(const ushort_t* g, ushort_t* l) {
  __builtin_amdgcn_global_load_lds((const __attribute__((address_space(1))) void*)g,
                                   (__attribute__((address_space(3))) void*)l, 16, 0, 0);
}

// ---------------- prep kernels ----------------
__global__ void hist_kernel(const int* __restrict__ src, const int* __restrict__ dst,
                            int* __restrict__ deg_out, int* __restrict__ deg_in) {
  int e = blockIdx.x * 256 + threadIdx.x;
  if (e < N_EDGES) {
    atomicAdd(&deg_out[src[e]], 1);
    atomicAdd(&deg_in[dst[e]], 1);
  }
}

__global__ void norm_kernel(const int* __restrict__ deg_out, const int* __restrict__ deg_in,
                            float* __restrict__ norm_out, float* __restrict__ norm_in) {
  int v = blockIdx.x * 256 + threadIdx.x;
  if (v < N_NODES) {
    norm_out[v] = rsqrtf((float)max(deg_out[v], 1));
    norm_in[v]  = rsqrtf((float)max(deg_in[v], 1));
  }
}

__global__ void scan1_kernel(const int* __restrict__ deg_in, int* __restrict__ bsums) {
  __shared__ int sred[256];
  int t0 = blockIdx.x * 1024 + threadIdx.x * 4;
  int s = 0;
#pragma unroll
  for (int i = 0; i < 4; i++) { int v = t0 + i; s += (v < N_NODES) ? deg_in[v] : 0; }
  sred[threadIdx.x] = s; __syncthreads();
  for (int off = 128; off > 0; off >>= 1) {
    if (threadIdx.x < off) sred[threadIdx.x] += sred[threadIdx.x + off];
    __syncthreads();
  }
  if (threadIdx.x == 0) bsums[blockIdx.x] = sred[0];
}

__global__ void scan2_kernel(const int* __restrict__ bsums, int* __restrict__ bofs,
                             int* __restrict__ row_ptr, int nb) {
  if (threadIdx.x == 0 && blockIdx.x == 0) {
    int run = 0;
    for (int i = 0; i < nb; i++) { bofs[i] = run; run += bsums[i]; }
    row_ptr[N_NODES] = run;
  }
}

__global__ void scan3_kernel(const int* __restrict__ deg_in, const int* __restrict__ bofs,
                             int* __restrict__ row_ptr) {
  __shared__ int ssc[256];
  int t0 = blockIdx.x * 1024 + threadIdx.x * 4;
  int v4[4]; int s = 0;
#pragma unroll
  for (int i = 0; i < 4; i++) { int v = t0 + i; v4[i] = (v < N_NODES) ? deg_in[v] : 0; s += v4[i]; }
  ssc[threadIdx.x] = s; __syncthreads();
  for (int off = 1; off < 256; off <<= 1) {
    int t = (threadIdx.x >= off) ? ssc[threadIdx.x - off] : 0;
    __syncthreads();
    ssc[threadIdx.x] += t;
    __syncthreads();
  }
  int ex = ssc[threadIdx.x] - s + bofs[blockIdx.x];
#pragma unroll
  for (int i = 0; i < 4; i++) {
    int v = t0 + i;
    if (v < N_NODES) { row_ptr[v] = ex; ex += v4[i]; }
  }
}

__global__ void csr_fill_kernel(const int* __restrict__ src, const int* __restrict__ dst,
                                const int* __restrict__ row_ptr, int* __restrict__ fill,
                                int* __restrict__ csr) {
  int e = blockIdx.x * 256 + threadIdx.x;
  if (e < N_EDGES) {
    int d = dst[e];
    int slot = atomicAdd(&fill[d], 1);
    csr[row_ptr[d] + slot] = src[e];
  }
}

// ---------- W swizzle into MFMA B-fragment order (single bf16, 10 KB per (m,kc)) ----------
__global__ void wtrans_kernel(const float* __restrict__ W_emb, const float* __restrict__ Ws,
                              ushort_t* __restrict__ Wh) {
  int idx = blockIdx.x * 256 + threadIdx.x;
  if (idx >= 5 * 5 * 10 * 64 * 8) return;
  int j = idx & 7;
  int t = idx >> 3;
  int lane = t & 63; t >>= 6;
  int nt = t % 10; t /= 10;
  int kc = t % 5;
  int m = t / 5;
  const float* W = (m == 0) ? W_emb : Ws + (size_t)(m - 1) * DIM * DIM;
  int k = kc * 32 + (lane >> 4) * 8 + j;
  int n = nt * 16 + (lane & 15);
  float w = (k < DIM && n < DIM) ? W[k * DIM + n] : 0.f;
  Wh[(size_t)(((m * 5 + kc) * 10 + nt) * 64 + lane) * 8 + j] = f2bf(w);
}

// in-register A-fragment from fp32 row (RNE pack)
__device__ inline bf16x8 make_frag(const float* __restrict__ nf, int row, int kc, int quad) {
  union { bf16x8 v; ushort_t u[8]; } r;
  const float* p = nf + (size_t)row * DIM + kc * 32 + quad * 8;
  int c0 = kc * 32 + quad * 8;
  if (c0 + 8 <= DIM) {
    float2 q0 = *(const float2*)(p);
    float2 q1 = *(const float2*)(p + 2);
    float2 q2 = *(const float2*)(p + 4);
    float2 q3 = *(const float2*)(p + 6);
    r.u[0] = f2bf(q0.x); r.u[1] = f2bf(q0.y); r.u[2] = f2bf(q1.x); r.u[3] = f2bf(q1.y);
    r.u[4] = f2bf(q2.x); r.u[5] = f2bf(q2.y); r.u[6] = f2bf(q3.x); r.u[7] = f2bf(q3.y);
  } else {
#pragma unroll
    for (int j = 0; j < 8; j++) r.u[j] = (c0 + j < DIM) ? f2bf(p[j]) : (ushort_t)0;
  }
  return r.v;
}

// ------------- embedding GEMM: 256-row / 512-thread blocks (unchanged from R6) -------------
__global__ __launch_bounds__(512, 4) void gemm_embed_kernel(
    const float* __restrict__ nf, const ushort_t* __restrict__ Wh,
    const float* __restrict__ bias, ushort_t* __restrict__ hbf) {
  __shared__ __align__(16) ushort_t sW[25600];   // all 5 kc slices, 50 KB
  int wave = threadIdx.x >> 6, lane = threadIdx.x & 63;
  int quad = lane >> 4, l16 = lane & 15;
  int m0 = blockIdx.x * 256 + wave * 32;
  int ra = min(m0 + l16, N_NODES - 1);
  int rb = min(m0 + 16 + l16, N_NODES - 1);

#pragma unroll
  for (int i = 0; i < 7; i++) {
    int idx = threadIdx.x + i * 512;
    if (idx < 3200) async_cp16(Wh + idx * 8, sW + idx * 8);
  }
  __syncthreads();

  floatx4 acc[2][10];
#pragma unroll
  for (int s = 0; s < 2; s++)
#pragma unroll
    for (int nt = 0; nt < 10; nt++) acc[s][nt] = (floatx4){0.f, 0.f, 0.f, 0.f};

#pragma unroll 1   // keep VGPR <=128
  for (int kc = 0; kc < 5; kc++) {
    bf16x8 a0 = make_frag(nf, ra, kc, quad);
    bf16x8 a1 = make_frag(nf, rb, kc, quad);
    const ushort_t* bp = &sW[kc * 5120 + lane * 8];
#pragma unroll
    for (int nt = 0; nt < 10; nt++) {
      bf16x8 bh = *(const bf16x8*)(bp + nt * 512);
      acc[0][nt] = __builtin_amdgcn_mfma_f32_16x16x32_bf16(a0, bh, acc[0][nt], 0, 0, 0);
      acc[1][nt] = __builtin_amdgcn_mfma_f32_16x16x32_bf16(a1, bh, acc[1][nt], 0, 0, 0);
    }
  }

#pragma unroll
  for (int nt = 0; nt < 10; nt++) {
    int c = nt * 16 + l16;
    float b = (c < DIM) ? bias[c] : 0.f;
#pragma unroll
    for (int s = 0; s < 2; s++)
#pragma unroll
      for (int r = 0; r < 4; r++) {
        int row = m0 + s * 16 + quad * 4 + r;
        hbf[(size_t)row * APAD + c] = f2bf(acc[s][nt][r] + b);
      }
  }
}

// ------- LAYER GEMM fused with BN+ReLU+residual via grid barrier (co-resident grid) -------
// grid 391 <= capacity 512 (launch_bounds(512,4) -> <=128 VGPR -> 16 waves/CU = 2 blocks/CU).
// Stats: device-scope atomicAdd; barrier + post-sync reads: agent-scope __hip_atomic ops
// (per-XCD L2 not coherent for plain loads). tmpb + bn_kernel eliminated.
__global__ __launch_bounds__(512, 4) void gemm_kernel(
    const ushort_t* __restrict__ Abf, const ushort_t* __restrict__ Wh,
    const float* __restrict__ bias, const float* __restrict__ snorm,
    const float* __restrict__ gamma, const float* __restrict__ beta,
    ushort_t* __restrict__ hbf, float* __restrict__ stats,
    int* __restrict__ bar, int nblocks) {
  __shared__ __align__(16) ushort_t sW[25600];   // all 5 kc slices, 50 KB
  __shared__ float sred[2 * DIM];                // partials, then reused as sc/sh
  int wave = threadIdx.x >> 6, lane = threadIdx.x & 63;
  int quad = lane >> 4, l16 = lane & 15;
  int m0 = blockIdx.x * 256 + wave * 32;
  int ra = min(m0 + l16, N_NODES - 1);
  int rb = min(m0 + 16 + l16, N_NODES - 1);
  const ushort_t* ap0 = Abf + (size_t)ra * APAD + quad * 8;
  const ushort_t* ap1 = Abf + (size_t)rb * APAD + quad * 8;

#pragma unroll
  for (int i = 0; i < 7; i++) {
    int idx = threadIdx.x + i * 512;
    if (idx < 3200) async_cp16(Wh + idx * 8, sW + idx * 8);
  }
  bf16x8 na0 = *(const bf16x8*)(ap0);
  bf16x8 na1 = *(const bf16x8*)(ap1);
  for (int i = threadIdx.x; i < 2 * DIM; i += 512) sred[i] = 0.f;
  __syncthreads();

  floatx4 acc[2][10];
#pragma unroll
  for (int s = 0; s < 2; s++)
#pragma unroll
    for (int nt = 0; nt < 10; nt++) acc[s][nt] = (floatx4){0.f, 0.f, 0.f, 0.f};

#pragma unroll 1   // keep VGPR <=128
  for (int kc = 0; kc < 5; kc++) {
    bf16x8 a0 = na0, a1 = na1;
    if (kc < 4) {
      na0 = *(const bf16x8*)(ap0 + (kc + 1) * 32);
      na1 = *(const bf16x8*)(ap1 + (kc + 1) * 32);
    }
    const ushort_t* bp = &sW[kc * 5120 + lane * 8];
#pragma unroll
    for (int nt = 0; nt < 10; nt++) {
      bf16x8 bh = *(const bf16x8*)(bp + nt * 512);
      acc[0][nt] = __builtin_amdgcn_mfma_f32_16x16x32_bf16(a0, bh, acc[0][nt], 0, 0, 0);
      acc[1][nt] = __builtin_amdgcn_mfma_f32_16x16x32_bf16(a1, bh, acc[1][nt], 0, 0, 0);
    }
  }

  float sn[2][4];
#pragma unroll
  for (int s = 0; s < 2; s++)
#pragma unroll
    for (int r = 0; r < 4; r++) sn[s][r] = snorm[min(m0 + s * 16 + quad * 4 + r, N_NODES - 1)];

  // per-block stats into LDS
#pragma unroll
  for (int nt = 0; nt < 10; nt++) {
    int c = nt * 16 + l16;
    if (c < DIM) {
      float b = bias[c];
      float ssum = 0.f, ssq = 0.f;
#pragma unroll
      for (int s = 0; s < 2; s++)
#pragma unroll
        for (int r = 0; r < 4; r++) {
          int row = m0 + s * 16 + quad * 4 + r;
          if (row < N_NODES) {
            float val = (acc[s][nt][r] + b) * sn[s][r];
            ssum += val; ssq += val * val;
          }
        }
      ssum += __shfl_xor(ssum, 16, 64); ssum += __shfl_xor(ssum, 32, 64);
      ssq  += __shfl_xor(ssq, 16, 64);  ssq  += __shfl_xor(ssq, 32, 64);
      if (quad == 0) {
        atomicAdd(&sred[c], ssum);
        atomicAdd(&sred[DIM + c], ssq);
      }
    }
  }
  __syncthreads();
  // dump partials to global (device-scope atomics)
  float* stp = stats + (blockIdx.x & (ST_PART - 1)) * 2 * DIM;
  for (int i = threadIdx.x; i < 2 * DIM; i += 512) atomicAdd(&stp[i], sred[i]);
  __threadfence();

  // ---- grid barrier (all blocks co-resident by construction) ----
  __syncthreads();   // drains each thread's vmcnt -> atomics complete
  if (threadIdx.x == 0) {
    int my = __hip_atomic_load(bar + 1, __ATOMIC_RELAXED, __HIP_MEMORY_SCOPE_AGENT);
    int a = __hip_atomic_fetch_add(bar, 1, __ATOMIC_ACQ_REL, __HIP_MEMORY_SCOPE_AGENT);
    if (a == nblocks - 1) {
      __hip_atomic_store(bar, 0, __ATOMIC_RELAXED, __HIP_MEMORY_SCOPE_AGENT);
      __hip_atomic_fetch_add(bar + 1, 1, __ATOMIC_RELEASE, __HIP_MEMORY_SCOPE_AGENT);
    } else {
      while (__hip_atomic_load(bar + 1, __ATOMIC_ACQUIRE, __HIP_MEMORY_SCOPE_AGENT) == my)
        __builtin_amdgcn_s_sleep(8);
    }
  }
  __syncthreads();

  // BN coefficients from complete stats (agent-scope loads bypass stale L2)
  if (threadIdx.x < DIM) {
    int c = threadIdx.x;
    float su = 0.f, sq = 0.f;
#pragma unroll
    for (int p = 0; p < ST_PART; p++) {
      const float* sp = stats + p * 2 * DIM;
      su += __hip_atomic_load(&sp[c], __ATOMIC_RELAXED, __HIP_MEMORY_SCOPE_AGENT);
      sq += __hip_atomic_load(&sp[DIM + c], __ATOMIC_RELAXED, __HIP_MEMORY_SCOPE_AGENT);
    }
    float mu = su * (1.f / N_NODES);
    float var = sq * (1.f / N_NODES) - mu * mu;
    float sc = gamma[c] * rsqrtf(var + BN_EPS);
    sred[c] = sc;
    sred[DIM + c] = beta[c] - mu * sc;
  }
  __syncthreads();

  // epilogue: BN + ReLU + residual, write hbf (pad rows garbage-safe, never read)
#pragma unroll
  for (int nt = 0; nt < 10; nt++) {
    int c = nt * 16 + l16;
    float b  = (c < DIM) ? bias[c] : 0.f;
    float sc = (c < DIM) ? sred[c] : 0.f;
    float sh = (c < DIM) ? sred[DIM + c] : 0.f;
#pragma unroll
    for (int s = 0; s < 2; s++)
#pragma unroll
      for (int r = 0; r < 4; r++) {
        int row = m0 + s * 16 + quad * 4 + r;
        float val = (acc[s][nt][r] + b) * sn[s][r];
        float x = fmaxf(fmaf(val, sc, sh), 0.f);
        size_t idx = (size_t)row * APAD + c;
        hbf[idx] = f2bf(bf2f(hbf[idx]) + x);
      }
  }
}

// ------- aggregation: one wave per node, bf16 gather, per-edge norm_out scale, 4-deep -------
__global__ __launch_bounds__(256) void agg_kernel(
    const ushort_t* __restrict__ hbf, const int* __restrict__ row_ptr,
    const int* __restrict__ csr, const float* __restrict__ norm_out,
    const float* __restrict__ norm_in, ushort_t* __restrict__ xb) {
  int wid = threadIdx.x >> 6, lane = threadIdx.x & 63;
  int v = blockIdx.x * 4 + wid;
  if (v >= N_NODES) return;
  int e0 = row_ptr[v], e1 = row_ptr[v + 1];
  bool act = lane < 40;
  int col8 = lane * 4;  // ushort offset within row
  float a0 = 0.f, a1 = 0.f, a2 = 0.f, a3 = 0.f;
  float b0 = 0.f, b1 = 0.f, b2 = 0.f, b3 = 0.f;
  float c0 = 0.f, c1 = 0.f, c2 = 0.f, c3 = 0.f;
  float d0 = 0.f, d1 = 0.f, d2 = 0.f, d3 = 0.f;
  int e = e0;
  for (; e + 3 < e1; e += 4) {
    int s0 = csr[e], s1 = csr[e + 1], s2 = csr[e + 2], s3 = csr[e + 3];
    float n0 = norm_out[s0], n1 = norm_out[s1], n2 = norm_out[s2], n3 = norm_out[s3];
    if (act) {
      uint2 u0 = *(const uint2*)(hbf + (size_t)s0 * APAD + col8);
      uint2 u1 = *(const uint2*)(hbf + (size_t)s1 * APAD + col8);
      uint2 u2 = *(const uint2*)(hbf + (size_t)s2 * APAD + col8);
      uint2 u3 = *(const uint2*)(hbf + (size_t)s3 * APAD + col8);
      a0 = fmaf(bflo(u0.x), n0, a0); a1 = fmaf(bfhi(u0.x), n0, a1);
      a2 = fmaf(bflo(u0.y), n0, a2); a3 = fmaf(bfhi(u0.y), n0, a3);
      b0 = fmaf(bflo(u1.x), n1, b0); b1 = fmaf(bfhi(u1.x), n1, b1);
      b2 = fmaf(bflo(u1.y), n1, b2); b3 = fmaf(bfhi(u1.y), n1, b3);
      c0 = fmaf(bflo(u2.x), n2, c0); c1 = fmaf(bfhi(u2.x), n2, c1);
      c2 = fmaf(bflo(u2.y), n2, c2); c3 = fmaf(bfhi(u2.y), n2, c3);
      d0 = fmaf(bflo(u3.x), n3, d0); d1 = fmaf(bfhi(u3.x), n3, d1);
      d2 = fmaf(bflo(u3.y), n3, d2); d3 = fmaf(bfhi(u3.y), n3, d3);
    }
  }
  for (; e < e1; e++) {
    int s0 = csr[e];
    float n0 = norm_out[s0];
    if (act) {
      uint2 u0 = *(const uint2*)(hbf + (size_t)s0 * APAD + col8);
      a0 = fmaf(bflo(u0.x), n0, a0); a1 = fmaf(bfhi(u0.x), n0, a1);
      a2 = fmaf(bflo(u0.y), n0, a2); a3 = fmaf(bfhi(u0.y), n0, a3);
    }
  }
  if (act) {
    float ni = norm_in[v];
    uint2 o;
    o.x = pack2bf((a0 + b0 + c0 + d0) * ni, (a1 + b1 + c1 + d1) * ni);
    o.y = pack2bf((a2 + b2 + c2 + d2) * ni, (a3 + b3 + c3 + d3) * ni);
    *(uint2*)((uint_t*)(xb + (size_t)v * APAD) + lane * 2) = o;
  }
}

// ---------------- per-graph sum of final h (BN already applied in gemm) ----------------
__global__ __launch_bounds__(192) void gsum_kernel(
    const ushort_t* __restrict__ hbf, const int* __restrict__ gids,
    float* __restrict__ hgp) {
  int t = threadIdx.x;
  if (t > DIM) return;
  int r0 = blockIdx.x * 64;
  int part = blockIdx.x & (GS_PART - 1);
  float accv = 0.f;
  int g_prev = gids[r0];
  for (int rr = 0; rr < 64; rr++) {
    int r = r0 + rr;
    if (r >= N_NODES) break;
    int g = gids[r];
    if (g != g_prev) {
      atomicAdd(&hgp[(size_t)(part * N_GRAPHS + g_prev) * GS_STRIDE + t], accv);
      accv = 0.f; g_prev = g;
    }
    accv += (t < DIM) ? bf2f(hbf[(size_t)r * APAD + t]) : 1.f;
  }
  atomicAdd(&hgp[(size_t)(part * N_GRAPHS + g_prev) * GS_STRIDE + t], accv);
}

// ---------------- fused mean + MLP readout: one block per graph ----------------
__global__ __launch_bounds__(256) void mlp_kernel(
    const float* __restrict__ hgp,
    const float* __restrict__ W1, const float* __restrict__ b1,
    const float* __restrict__ W2, const float* __restrict__ b2,
    const float* __restrict__ W3, const float* __restrict__ b3,
    float* __restrict__ out) {
  __shared__ float hrow[DIM];
  __shared__ float x1[73];
  __shared__ float x2[36];
  int g = blockIdx.x;
  int t = threadIdx.x;
  if (t < DIM) {
    float s = 0.f, cnt = 0.f;
#pragma unroll
    for (int p = 0; p < GS_PART; p++) {
      const float* row = hgp + (size_t)(p * N_GRAPHS + g) * GS_STRIDE;
      s += row[t];
      cnt += row[DIM];
    }
    hrow[t] = s / cnt;
  }
  __syncthreads();
  if (t < 73) {
    float s = b1[t];
    for (int k = 0; k < DIM; k++) s = fmaf(hrow[k], W1[k * 73 + t], s);
    x1[t] = s > 0.f ? s : 0.f;
  }
  __syncthreads();
  if (t < 36) {
    float s = b2[t];
    for (int k = 0; k < 73; k++) s = fmaf(x1[k], W2[k * 36 + t], s);
    x2[t] = s > 0.f ? s : 0.f;
  }
  __syncthreads();
  if (t < 10) {
    float s = b3[t];
    for (int k = 0; k < 36; k++) s = fmaf(x2[k], W3[k * 10 + t], s);
    out[g * 10 + t] = s;
  }
}

extern "C" void kernel_launch(void* const* d_in, const int* in_sizes, int n_in,
                              void* d_out, int out_size, void* d_ws, size_t ws_size,
                              hipStream_t stream) {
  const float* nodes_feat = (const float*)d_in[0];
  const float* snorm  = (const float*)d_in[1];
  const float* W_emb  = (const float*)d_in[2];
  const float* b_emb  = (const float*)d_in[3];
  const float* Ws     = (const float*)d_in[4];
  const float* bs     = (const float*)d_in[5];
  const float* gammas = (const float*)d_in[6];
  const float* betas  = (const float*)d_in[7];
  const float* W1 = (const float*)d_in[8];
  const float* b1 = (const float*)d_in[9];
  const float* W2 = (const float*)d_in[10];
  const float* b2 = (const float*)d_in[11];
  const float* W3 = (const float*)d_in[12];
  const float* b3 = (const float*)d_in[13];
  const int* src  = (const int*)d_in[14];
  const int* dst  = (const int*)d_in[15];
  const int* gids = (const int*)d_in[16];
  float* out = (float*)d_out;

  const int GB = (N_NODES + 255) / 256;        // 391 gemm blocks, 256 rows each
  const int NPADROWS = GB * 256;               // 100096

  char* base = (char*)d_ws;
  size_t off = 0;
  auto alloc = [&](size_t bytes) { void* p = base + off; off += (bytes + 255) & ~size_t(255); return p; };
  ushort_t* hbf  = (ushort_t*)alloc((size_t)NPADROWS * APAD * 2);  // bf16 residual stream
  ushort_t* xb   = (ushort_t*)alloc((size_t)N_NODES * APAD * 2);   // bf16 GEMM input
  char* zstart = base + off;
  int* deg_out = (int*)alloc(N_NODES * 4);
  int* deg_in  = (int*)alloc(N_NODES * 4);
  int* fill    = (int*)alloc(N_NODES * 4);
  float* stats = (float*)alloc(4 * ST_PART * 2 * DIM * 4);  // per layer: ST_PART x [sum,sumsq]
  float* hgp   = (float*)alloc((size_t)GS_PART * N_GRAPHS * GS_STRIDE * 4);
  int* gbar    = (int*)alloc(4 * 16 * 4);                   // per-layer {count,gen} (64B apart)
  size_t zbytes = (size_t)((base + off) - zstart);
  int* row_ptr = (int*)alloc((N_NODES + 1) * 4);
  float* norm_out = (float*)alloc(N_NODES * 4);
  float* norm_in  = (float*)alloc(N_NODES * 4);
  int* csr   = (int*)alloc((size_t)N_EDGES * 4);
  int* bsums = (int*)alloc(128 * 4);
  int* bofs  = (int*)alloc(128 * 4);
  ushort_t* Wh = (ushort_t*)alloc((size_t)5 * 5 * 10 * 64 * 8 * 2);  // single bf16

  hipMemsetAsync(zstart, 0, zbytes, stream);

  hist_kernel<<<(N_EDGES + 255) / 256, 256, 0, stream>>>(src, dst, deg_out, deg_in);
  norm_kernel<<<(N_NODES + 255) / 256, 256, 0, stream>>>(deg_out, deg_in, norm_out, norm_in);
  int nb = (N_NODES + 1023) / 1024;
  scan1_kernel<<<nb, 256, 0, stream>>>(deg_in, bsums);
  scan2_kernel<<<1, 64, 0, stream>>>(bsums, bofs, row_ptr, nb);
  scan3_kernel<<<nb, 256, 0, stream>>>(deg_in, bofs, row_ptr);
  csr_fill_kernel<<<(N_EDGES + 255) / 256, 256, 0, stream>>>(src, dst, row_ptr, fill, csr);
  wtrans_kernel<<<(5 * 5 * 10 * 64 * 8 + 255) / 256, 256, 0, stream>>>(W_emb, Ws, Wh);

  const size_t WHM = (size_t)5 * 10 * 64 * 8;      // Wh elems per matrix (25600)

  gemm_embed_kernel<<<GB, 512, 0, stream>>>(nodes_feat, Wh, b_emb, hbf);

  for (int l = 0; l < 4; l++) {
    float* st = stats + (size_t)l * ST_PART * 2 * DIM;
    agg_kernel<<<(N_NODES + 3) / 4, 256, 0, stream>>>(hbf, row_ptr, csr, norm_out, norm_in, xb);
    gemm_kernel<<<GB, 512, 0, stream>>>(xb, Wh + (size_t)(l + 1) * WHM, bs + l * DIM,
                                        snorm, gammas + l * DIM, betas + l * DIM,
                                        hbf, st, gbar + l * 16, GB);
  }

  gsum_kernel<<<(N_NODES + 63) / 64, 192, 0, stream>>>(hbf, gids, hgp);
  mlp_kernel<<<N_GRAPHS, 256, 0, stream>>>(hgp, W1, b1, W2, b2, W3, b3, out);
}

// Round 8
// 598.373 us; speedup vs baseline: 1.7118x; 1.7118x over previous
//
#include <hip/hip_runtime.h>

#define N_NODES 100000
#define N_EDGES 500000
#define N_GRAPHS 100
#define DIM 146
#define APAD 160        // padded bf16 row stride (16B-aligned, 5 k-chunks of 32)
#define TPW 160         // tmp bf16 row stride (ushorts)
#define BN_EPS 1e-5f
#define GS_PART 8
#define GS_STRIDE 147   // 146 cols + 1 count slot
#define ST_PART 4       // stat-atomic partitions

typedef __bf16 bf16x8 __attribute__((ext_vector_type(8)));
typedef float floatx4 __attribute__((ext_vector_type(4)));
typedef unsigned short ushort_t;
typedef unsigned int uint_t;

__device__ inline ushort_t f2bf(float x) {
  uint_t u = __float_as_uint(x);
  uint_t r = (u + 0x7fffu + ((u >> 16) & 1u)) >> 16;   // RNE
  return (ushort_t)r;
}
__device__ inline float bf2f(ushort_t b) { return __uint_as_float((uint_t)b << 16); }
__device__ inline uint_t pack2bf(float a, float b) {
  return (uint_t)f2bf(a) | ((uint_t)f2bf(b) << 16);
}
__device__ inline float bflo(uint_t u) { return __uint_as_float(u << 16); }
__device__ inline float bfhi(uint_t u) { return __uint_as_float(u & 0xffff0000u); }

// async global->LDS, 16 B per lane (global_load_lds_dwordx4)
__device__ inline void async_cp16(const ushort_t* g, ushort_t* l) {
  __builtin_amdgcn_global_load_lds((const __attribute__((address_space(1))) void*)g,
                                   (__attribute__((address_space(3))) void*)l, 16, 0, 0);
}

// ---------------- prep kernels ----------------
__global__ void hist_kernel(const int* __restrict__ src, const int* __restrict__ dst,
                            int* __restrict__ deg_out, int* __restrict__ deg_in) {
  int e = blockIdx.x * 256 + threadIdx.x;
  if (e < N_EDGES) {
    atomicAdd(&deg_out[src[e]], 1);
    atomicAdd(&deg_in[dst[e]], 1);
  }
}

__global__ void norm_kernel(const int* __restrict__ deg_out, const int* __restrict__ deg_in,
                            float* __restrict__ norm_out, float* __restrict__ norm_in) {
  int v = blockIdx.x * 256 + threadIdx.x;
  if (v < N_NODES) {
    norm_out[v] = rsqrtf((float)max(deg_out[v], 1));
    norm_in[v]  = rsqrtf((float)max(deg_in[v], 1));
  }
}

__global__ void scan1_kernel(const int* __restrict__ deg_in, int* __restrict__ bsums) {
  __shared__ int sred[256];
  int t0 = blockIdx.x * 1024 + threadIdx.x * 4;
  int s = 0;
#pragma unroll
  for (int i = 0; i < 4; i++) { int v = t0 + i; s += (v < N_NODES) ? deg_in[v] : 0; }
  sred[threadIdx.x] = s; __syncthreads();
  for (int off = 128; off > 0; off >>= 1) {
    if (threadIdx.x < off) sred[threadIdx.x] += sred[threadIdx.x + off];
    __syncthreads();
  }
  if (threadIdx.x == 0) bsums[blockIdx.x] = sred[0];
}

__global__ void scan2_kernel(const int* __restrict__ bsums, int* __restrict__ bofs,
                             int* __restrict__ row_ptr, int nb) {
  if (threadIdx.x == 0 && blockIdx.x == 0) {
    int run = 0;
    for (int i = 0; i < nb; i++) { bofs[i] = run; run += bsums[i]; }
    row_ptr[N_NODES] = run;
  }
}

__global__ void scan3_kernel(const int* __restrict__ deg_in, const int* __restrict__ bofs,
                             int* __restrict__ row_ptr) {
  __shared__ int ssc[256];
  int t0 = blockIdx.x * 1024 + threadIdx.x * 4;
  int v4[4]; int s = 0;
#pragma unroll
  for (int i = 0; i < 4; i++) { int v = t0 + i; v4[i] = (v < N_NODES) ? deg_in[v] : 0; s += v4[i]; }
  ssc[threadIdx.x] = s; __syncthreads();
  for (int off = 1; off < 256; off <<= 1) {
    int t = (threadIdx.x >= off) ? ssc[threadIdx.x - off] : 0;
    __syncthreads();
    ssc[threadIdx.x] += t;
    __syncthreads();
  }
  int ex = ssc[threadIdx.x] - s + bofs[blockIdx.x];
#pragma unroll
  for (int i = 0; i < 4; i++) {
    int v = t0 + i;
    if (v < N_NODES) { row_ptr[v] = ex; ex += v4[i]; }
  }
}

__global__ void csr_fill_kernel(const int* __restrict__ src, const int* __restrict__ dst,
                                const int* __restrict__ row_ptr, int* __restrict__ fill,
                                int* __restrict__ csr) {
  int e = blockIdx.x * 256 + threadIdx.x;
  if (e < N_EDGES) {
    int d = dst[e];
    int slot = atomicAdd(&fill[d], 1);
    csr[row_ptr[d] + slot] = src[e];
  }
}

// ---------- W swizzle into MFMA B-fragment order (single bf16, 10 KB per (m,kc)) ----------
__global__ void wtrans_kernel(const float* __restrict__ W_emb, const float* __restrict__ Ws,
                              ushort_t* __restrict__ Wh) {
  int idx = blockIdx.x * 256 + threadIdx.x;
  if (idx >= 5 * 5 * 10 * 64 * 8) return;
  int j = idx & 7;
  int t = idx >> 3;
  int lane = t & 63; t >>= 6;
  int nt = t % 10; t /= 10;
  int kc = t % 5;
  int m = t / 5;
  const float* W = (m == 0) ? W_emb : Ws + (size_t)(m - 1) * DIM * DIM;
  int k = kc * 32 + (lane >> 4) * 8 + j;
  int n = nt * 16 + (lane & 15);
  float w = (k < DIM && n < DIM) ? W[k * DIM + n] : 0.f;
  Wh[(size_t)(((m * 5 + kc) * 10 + nt) * 64 + lane) * 8 + j] = f2bf(w);
}

// in-register A-fragment from fp32 row (RNE pack)
__device__ inline bf16x8 make_frag(const float* __restrict__ nf, int row, int kc, int quad) {
  union { bf16x8 v; ushort_t u[8]; } r;
  const float* p = nf + (size_t)row * DIM + kc * 32 + quad * 8;
  int c0 = kc * 32 + quad * 8;
  if (c0 + 8 <= DIM) {
    float2 q0 = *(const float2*)(p);
    float2 q1 = *(const float2*)(p + 2);
    float2 q2 = *(const float2*)(p + 4);
    float2 q3 = *(const float2*)(p + 6);
    r.u[0] = f2bf(q0.x); r.u[1] = f2bf(q0.y); r.u[2] = f2bf(q1.x); r.u[3] = f2bf(q1.y);
    r.u[4] = f2bf(q2.x); r.u[5] = f2bf(q2.y); r.u[6] = f2bf(q3.x); r.u[7] = f2bf(q3.y);
  } else {
#pragma unroll
    for (int j = 0; j < 8; j++) r.u[j] = (c0 + j < DIM) ? f2bf(p[j]) : (ushort_t)0;
  }
  return r.v;
}

// ------------- embedding GEMM: 256-row / 512-thread blocks (R6 form, unchanged) -------------
__global__ __launch_bounds__(512, 4) void gemm_embed_kernel(
    const float* __restrict__ nf, const ushort_t* __restrict__ Wh,
    const float* __restrict__ bias, ushort_t* __restrict__ hbf) {
  __shared__ __align__(16) ushort_t sW[25600];   // all 5 kc slices, 50 KB
  int wave = threadIdx.x >> 6, lane = threadIdx.x & 63;
  int quad = lane >> 4, l16 = lane & 15;
  int m0 = blockIdx.x * 256 + wave * 32;
  int ra = min(m0 + l16, N_NODES - 1);
  int rb = min(m0 + 16 + l16, N_NODES - 1);

#pragma unroll
  for (int i = 0; i < 7; i++) {
    int idx = threadIdx.x + i * 512;
    if (idx < 3200) async_cp16(Wh + idx * 8, sW + idx * 8);
  }
  __syncthreads();

  floatx4 acc[2][10];
#pragma unroll
  for (int s = 0; s < 2; s++)
#pragma unroll
    for (int nt = 0; nt < 10; nt++) acc[s][nt] = (floatx4){0.f, 0.f, 0.f, 0.f};

#pragma unroll 1   // keep VGPR <=128
  for (int kc = 0; kc < 5; kc++) {
    bf16x8 a0 = make_frag(nf, ra, kc, quad);
    bf16x8 a1 = make_frag(nf, rb, kc, quad);
    const ushort_t* bp = &sW[kc * 5120 + lane * 8];
#pragma unroll
    for (int nt = 0; nt < 10; nt++) {
      bf16x8 bh = *(const bf16x8*)(bp + nt * 512);
      acc[0][nt] = __builtin_amdgcn_mfma_f32_16x16x32_bf16(a0, bh, acc[0][nt], 0, 0, 0);
      acc[1][nt] = __builtin_amdgcn_mfma_f32_16x16x32_bf16(a1, bh, acc[1][nt], 0, 0, 0);
    }
  }

#pragma unroll
  for (int nt = 0; nt < 10; nt++) {
    int c = nt * 16 + l16;
    float b = (c < DIM) ? bias[c] : 0.f;
#pragma unroll
    for (int s = 0; s < 2; s++)
#pragma unroll
      for (int r = 0; r < 4; r++) {
        int row = m0 + s * 16 + quad * 4 + r;
        hbf[(size_t)row * APAD + c] = f2bf(acc[s][nt][r] + b);
      }
  }
}

// ------------- LAYER MFMA GEMM: A read from kc-major planes (dense, coalesced) -------------
// xb layout: 5 planes of [N_NODES][32] bf16. Per-kc A-load is 16 consecutive rows x 64 B
// contiguous -> 1 dense transaction per 16-lane group instead of 20 strided 16 B touches
// per 320 B row in the old row-major layout.
__global__ __launch_bounds__(512, 4) void gemm_kernel(
    const ushort_t* __restrict__ Abf, const ushort_t* __restrict__ Wh,
    const float* __restrict__ bias, const float* __restrict__ snorm,
    ushort_t* __restrict__ tmpb, float* __restrict__ stats) {
  __shared__ __align__(16) ushort_t sW[25600];   // all 5 kc slices, 50 KB
  __shared__ float sred[2 * DIM];
  const size_t PLN = (size_t)N_NODES * 32;       // elems per kc plane
  int wave = threadIdx.x >> 6, lane = threadIdx.x & 63;
  int quad = lane >> 4, l16 = lane & 15;
  int m0 = blockIdx.x * 256 + wave * 32;
  int ra = min(m0 + l16, N_NODES - 1);
  int rb = min(m0 + 16 + l16, N_NODES - 1);
  const ushort_t* ap0 = Abf + (size_t)ra * 32 + quad * 8;
  const ushort_t* ap1 = Abf + (size_t)rb * 32 + quad * 8;

#pragma unroll
  for (int i = 0; i < 7; i++) {
    int idx = threadIdx.x + i * 512;
    if (idx < 3200) async_cp16(Wh + idx * 8, sW + idx * 8);
  }
  // depth-1 pipelined A fragments (16 live regs instead of 40)
  bf16x8 na0 = *(const bf16x8*)(ap0);
  bf16x8 na1 = *(const bf16x8*)(ap1);
  for (int i = threadIdx.x; i < 2 * DIM; i += 512) sred[i] = 0.f;
  __syncthreads();

  floatx4 acc[2][10];
#pragma unroll
  for (int s = 0; s < 2; s++)
#pragma unroll
    for (int nt = 0; nt < 10; nt++) acc[s][nt] = (floatx4){0.f, 0.f, 0.f, 0.f};

#pragma unroll 1   // keep VGPR <=128: one kc in flight
  for (int kc = 0; kc < 5; kc++) {
    bf16x8 a0 = na0, a1 = na1;
    if (kc < 4) {
      na0 = *(const bf16x8*)(ap0 + (size_t)(kc + 1) * PLN);
      na1 = *(const bf16x8*)(ap1 + (size_t)(kc + 1) * PLN);
    }
    const ushort_t* bp = &sW[kc * 5120 + lane * 8];
#pragma unroll
    for (int nt = 0; nt < 10; nt++) {
      bf16x8 bh = *(const bf16x8*)(bp + nt * 512);
      acc[0][nt] = __builtin_amdgcn_mfma_f32_16x16x32_bf16(a0, bh, acc[0][nt], 0, 0, 0);
      acc[1][nt] = __builtin_amdgcn_mfma_f32_16x16x32_bf16(a1, bh, acc[1][nt], 0, 0, 0);
    }
  }

  float sn[2][4];
#pragma unroll
  for (int s = 0; s < 2; s++)
#pragma unroll
    for (int r = 0; r < 4; r++) sn[s][r] = snorm[min(m0 + s * 16 + quad * 4 + r, N_NODES - 1)];

#pragma unroll
  for (int nt = 0; nt < 10; nt++) {
    int c = nt * 16 + l16;
    float b = (c < DIM) ? bias[c] : 0.f;
    float ssum = 0.f, ssq = 0.f;
#pragma unroll
    for (int s = 0; s < 2; s++)
#pragma unroll
      for (int r = 0; r < 4; r++) {
        int row = m0 + s * 16 + quad * 4 + r;
        float val = (acc[s][nt][r] + b) * sn[s][r];
        tmpb[(size_t)row * TPW + c] = f2bf(val);
        if (c < DIM && row < N_NODES) { ssum += val; ssq += val * val; }
      }
    if (c < DIM) {
      ssum += __shfl_xor(ssum, 16, 64); ssum += __shfl_xor(ssum, 32, 64);
      ssq  += __shfl_xor(ssq, 16, 64);  ssq  += __shfl_xor(ssq, 32, 64);
      if (quad == 0) {
        atomicAdd(&sred[c], ssum);
        atomicAdd(&sred[DIM + c], ssq);
      }
    }
  }
  __syncthreads();
  float* stp = stats + (blockIdx.x & (ST_PART - 1)) * 2 * DIM;
  for (int i = threadIdx.x; i < 2 * DIM; i += 512) atomicAdd(&stp[i], sred[i]);
}

// ------- aggregation: one wave per node, bf16 gather; output to kc-major planes -------
__global__ __launch_bounds__(256) void agg_kernel(
    const ushort_t* __restrict__ hbf, const int* __restrict__ row_ptr,
    const int* __restrict__ csr, const float* __restrict__ norm_out,
    const float* __restrict__ norm_in, ushort_t* __restrict__ xb) {
  const size_t PLN = (size_t)N_NODES * 32;
  int wid = threadIdx.x >> 6, lane = threadIdx.x & 63;
  int v = blockIdx.x * 4 + wid;
  if (v >= N_NODES) return;
  int e0 = row_ptr[v], e1 = row_ptr[v + 1];
  bool act = lane < 40;
  int col8 = lane * 4;  // ushort offset within hbf row
  float a0 = 0.f, a1 = 0.f, a2 = 0.f, a3 = 0.f;
  float b0 = 0.f, b1 = 0.f, b2 = 0.f, b3 = 0.f;
  float c0 = 0.f, c1 = 0.f, c2 = 0.f, c3 = 0.f;
  float d0 = 0.f, d1 = 0.f, d2 = 0.f, d3 = 0.f;
  int e = e0;
  for (; e + 3 < e1; e += 4) {
    int s0 = csr[e], s1 = csr[e + 1], s2 = csr[e + 2], s3 = csr[e + 3];
    float n0 = norm_out[s0], n1 = norm_out[s1], n2 = norm_out[s2], n3 = norm_out[s3];
    if (act) {
      uint2 u0 = *(const uint2*)(hbf + (size_t)s0 * APAD + col8);
      uint2 u1 = *(const uint2*)(hbf + (size_t)s1 * APAD + col8);
      uint2 u2 = *(const uint2*)(hbf + (size_t)s2 * APAD + col8);
      uint2 u3 = *(const uint2*)(hbf + (size_t)s3 * APAD + col8);
      a0 = fmaf(bflo(u0.x), n0, a0); a1 = fmaf(bfhi(u0.x), n0, a1);
      a2 = fmaf(bflo(u0.y), n0, a2); a3 = fmaf(bfhi(u0.y), n0, a3);
      b0 = fmaf(bflo(u1.x), n1, b0); b1 = fmaf(bfhi(u1.x), n1, b1);
      b2 = fmaf(bflo(u1.y), n1, b2); b3 = fmaf(bfhi(u1.y), n1, b3);
      c0 = fmaf(bflo(u2.x), n2, c0); c1 = fmaf(bfhi(u2.x), n2, c1);
      c2 = fmaf(bflo(u2.y), n2, c2); c3 = fmaf(bfhi(u2.y), n2, c3);
      d0 = fmaf(bflo(u3.x), n3, d0); d1 = fmaf(bfhi(u3.x), n3, d1);
      d2 = fmaf(bflo(u3.y), n3, d2); d3 = fmaf(bfhi(u3.y), n3, d3);
    }
  }
  for (; e < e1; e++) {
    int s0 = csr[e];
    float n0 = norm_out[s0];
    if (act) {
      uint2 u0 = *(const uint2*)(hbf + (size_t)s0 * APAD + col8);
      a0 = fmaf(bflo(u0.x), n0, a0); a1 = fmaf(bfhi(u0.x), n0, a1);
      a2 = fmaf(bflo(u0.y), n0, a2); a3 = fmaf(bfhi(u0.y), n0, a3);
    }
  }
  if (act) {
    float ni = norm_in[v];
    uint2 o;
    o.x = pack2bf((a0 + b0 + c0 + d0) * ni, (a1 + b1 + c1 + d1) * ni);
    o.y = pack2bf((a2 + b2 + c2 + d2) * ni, (a3 + b3 + c3 + d3) * ni);
    // kc-major plane write: lane covers cols 4*lane..4*lane+3 -> plane lane>>3, offset (4*lane)&31
    int kc = lane >> 3;
    int cw = (lane & 7) * 4;
    *(uint2*)(xb + (size_t)kc * PLN + (size_t)v * 32 + cw) = o;
  }
}

// --- fused BN-prep + BN + ReLU + residual; bf16 in/out, uint4 (8 cols) per thread ---
__global__ __launch_bounds__(256) void bn_kernel(const ushort_t* __restrict__ tmpb,
                                                 const float* __restrict__ stats,
                                                 const float* __restrict__ gamma,
                                                 const float* __restrict__ beta,
                                                 ushort_t* __restrict__ hbf) {
  __shared__ float2 scs[80], shs[80];
  int t = threadIdx.x;
  if (t < 80) {
    float2 sc = make_float2(0.f, 0.f), sh = make_float2(0.f, 0.f);
    if (t < DIM / 2) {
      int c0 = 2 * t, c1 = c0 + 1;
      float su0 = 0.f, su1 = 0.f, sq0 = 0.f, sq1 = 0.f;
#pragma unroll
      for (int p = 0; p < ST_PART; p++) {
        const float* sp = stats + p * 2 * DIM;
        su0 += sp[c0]; su1 += sp[c1];
        sq0 += sp[DIM + c0]; sq1 += sp[DIM + c1];
      }
      float mu0 = su0 * (1.f / N_NODES), mu1 = su1 * (1.f / N_NODES);
      float v0 = sq0 * (1.f / N_NODES) - mu0 * mu0;
      float v1 = sq1 * (1.f / N_NODES) - mu1 * mu1;
      sc.x = gamma[c0] * rsqrtf(v0 + BN_EPS);
      sc.y = gamma[c1] * rsqrtf(v1 + BN_EPS);
      sh.x = beta[c0] - mu0 * sc.x;
      sh.y = beta[c1] - mu1 * sc.y;
    }
    scs[t] = sc; shs[t] = sh;
  }
  __syncthreads();
  int idx = blockIdx.x * 256 + t;
  if (idx >= N_NODES * 20) return;        // 20 uint4 per 160-ushort row
  int v = idx / 20, q = idx - v * 20;
  const uint4* tp = (const uint4*)(tmpb + (size_t)v * TPW);
  uint4* hp = (uint4*)(hbf + (size_t)v * APAD);
  uint4 tu = tp[q];
  uint4 hu = hp[q];
  uint4 o;
  {
    float2 sc = scs[q * 4 + 0], sh = shs[q * 4 + 0];
    float x0 = fmaxf(fmaf(bflo(tu.x), sc.x, sh.x), 0.f);
    float x1 = fmaxf(fmaf(bfhi(tu.x), sc.y, sh.y), 0.f);
    o.x = pack2bf(bflo(hu.x) + x0, bfhi(hu.x) + x1);
  }
  {
    float2 sc = scs[q * 4 + 1], sh = shs[q * 4 + 1];
    float x0 = fmaxf(fmaf(bflo(tu.y), sc.x, sh.x), 0.f);
    float x1 = fmaxf(fmaf(bfhi(tu.y), sc.y, sh.y), 0.f);
    o.y = pack2bf(bflo(hu.y) + x0, bfhi(hu.y) + x1);
  }
  {
    float2 sc = scs[q * 4 + 2], sh = shs[q * 4 + 2];
    float x0 = fmaxf(fmaf(bflo(tu.z), sc.x, sh.x), 0.f);
    float x1 = fmaxf(fmaf(bfhi(tu.z), sc.y, sh.y), 0.f);
    o.z = pack2bf(bflo(hu.z) + x0, bfhi(hu.z) + x1);
  }
  {
    float2 sc = scs[q * 4 + 3], sh = shs[q * 4 + 3];
    float x0 = fmaxf(fmaf(bflo(tu.w), sc.x, sh.x), 0.f);
    float x1 = fmaxf(fmaf(bfhi(tu.w), sc.y, sh.y), 0.f);
    o.w = pack2bf(bflo(hu.w) + x0, bfhi(hu.w) + x1);
  }
  hp[q] = o;
}

// ---------------- layer-3 fused: BN+ReLU+residual -> per-graph sum ----------------
__global__ __launch_bounds__(192) void gsum_kernel(
    const ushort_t* __restrict__ tmpb, const float* __restrict__ stats,
    const float* __restrict__ gamma, const float* __restrict__ beta,
    const ushort_t* __restrict__ hbf, const int* __restrict__ gids,
    float* __restrict__ hgp) {
  int t = threadIdx.x;
  if (t > DIM) return;
  float sc = 0.f, sh = 0.f;
  if (t < DIM) {
    float su = 0.f, sq = 0.f;
#pragma unroll
    for (int p = 0; p < ST_PART; p++) {
      const float* sp = stats + p * 2 * DIM;
      su += sp[t]; sq += sp[DIM + t];
    }
    float mu = su * (1.f / N_NODES);
    float var = sq * (1.f / N_NODES) - mu * mu;
    sc = gamma[t] * rsqrtf(var + BN_EPS);
    sh = beta[t] - mu * sc;
  }
  int r0 = blockIdx.x * 64;
  int part = blockIdx.x & (GS_PART - 1);
  float accv = 0.f;
  int g_prev = gids[r0];
  for (int rr = 0; rr < 64; rr++) {
    int r = r0 + rr;
    if (r >= N_NODES) break;
    int g = gids[r];
    if (g != g_prev) {
      atomicAdd(&hgp[(size_t)(part * N_GRAPHS + g_prev) * GS_STRIDE + t], accv);
      accv = 0.f; g_prev = g;
    }
    float val;
    if (t < DIM) {
      float x = fmaf(bf2f(tmpb[(size_t)r * TPW + t]), sc, sh);
      x = fmaxf(x, 0.f);
      val = bf2f(hbf[(size_t)r * APAD + t]) + x;
    } else {
      val = 1.f;
    }
    accv += val;
  }
  atomicAdd(&hgp[(size_t)(part * N_GRAPHS + g_prev) * GS_STRIDE + t], accv);
}

// ---------------- fused mean + MLP readout: one block per graph ----------------
__global__ __launch_bounds__(256) void mlp_kernel(
    const float* __restrict__ hgp,
    const float* __restrict__ W1, const float* __restrict__ b1,
    const float* __restrict__ W2, const float* __restrict__ b2,
    const float* __restrict__ W3, const float* __restrict__ b3,
    float* __restrict__ out) {
  __shared__ float hrow[DIM];
  __shared__ float x1[73];
  __shared__ float x2[36];
  int g = blockIdx.x;
  int t = threadIdx.x;
  if (t < DIM) {
    float s = 0.f, cnt = 0.f;
#pragma unroll
    for (int p = 0; p < GS_PART; p++) {
      const float* row = hgp + (size_t)(p * N_GRAPHS + g) * GS_STRIDE;
      s += row[t];
      cnt += row[DIM];
    }
    hrow[t] = s / cnt;
  }
  __syncthreads();
  if (t < 73) {
    float s = b1[t];
    for (int k = 0; k < DIM; k++) s = fmaf(hrow[k], W1[k * 73 + t], s);
    x1[t] = s > 0.f ? s : 0.f;
  }
  __syncthreads();
  if (t < 36) {
    float s = b2[t];
    for (int k = 0; k < 73; k++) s = fmaf(x1[k], W2[k * 36 + t], s);
    x2[t] = s > 0.f ? s : 0.f;
  }
  __syncthreads();
  if (t < 10) {
    float s = b3[t];
    for (int k = 0; k < 36; k++) s = fmaf(x2[k], W3[k * 10 + t], s);
    out[g * 10 + t] = s;
  }
}

extern "C" void kernel_launch(void* const* d_in, const int* in_sizes, int n_in,
                              void* d_out, int out_size, void* d_ws, size_t ws_size,
                              hipStream_t stream) {
  const float* nodes_feat = (const float*)d_in[0];
  const float* snorm  = (const float*)d_in[1];
  const float* W_emb  = (const float*)d_in[2];
  const float* b_emb  = (const float*)d_in[3];
  const float* Ws     = (const float*)d_in[4];
  const float* bs     = (const float*)d_in[5];
  const float* gammas = (const float*)d_in[6];
  const float* betas  = (const float*)d_in[7];
  const float* W1 = (const float*)d_in[8];
  const float* b1 = (const float*)d_in[9];
  const float* W2 = (const float*)d_in[10];
  const float* b2 = (const float*)d_in[11];
  const float* W3 = (const float*)d_in[12];
  const float* b3 = (const float*)d_in[13];
  const int* src  = (const int*)d_in[14];
  const int* dst  = (const int*)d_in[15];
  const int* gids = (const int*)d_in[16];
  float* out = (float*)d_out;

  const int GB = (N_NODES + 255) / 256;        // 391 gemm blocks, 256 rows each
  const int NPADROWS = GB * 256;               // 100096

  char* base = (char*)d_ws;
  size_t off = 0;
  auto alloc = [&](size_t bytes) { void* p = base + off; off += (bytes + 255) & ~size_t(255); return p; };
  ushort_t* hbf  = (ushort_t*)alloc((size_t)NPADROWS * APAD * 2);  // bf16 residual stream
  ushort_t* tmpb = (ushort_t*)alloc((size_t)NPADROWS * TPW * 2);   // bf16 GEMM output
  ushort_t* xb   = (ushort_t*)alloc((size_t)N_NODES * APAD * 2);   // bf16 GEMM input (5 kc planes)
  char* zstart = base + off;
  int* deg_out = (int*)alloc(N_NODES * 4);
  int* deg_in  = (int*)alloc(N_NODES * 4);
  int* fill    = (int*)alloc(N_NODES * 4);
  float* stats = (float*)alloc(4 * ST_PART * 2 * DIM * 4);  // per layer: ST_PART x [sum,sumsq]
  float* hgp   = (float*)alloc((size_t)GS_PART * N_GRAPHS * GS_STRIDE * 4);
  size_t zbytes = (size_t)((base + off) - zstart);
  int* row_ptr = (int*)alloc((N_NODES + 1) * 4);
  float* norm_out = (float*)alloc(N_NODES * 4);
  float* norm_in  = (float*)alloc(N_NODES * 4);
  int* csr   = (int*)alloc((size_t)N_EDGES * 4);
  int* bsums = (int*)alloc(128 * 4);
  int* bofs  = (int*)alloc(128 * 4);
  ushort_t* Wh = (ushort_t*)alloc((size_t)5 * 5 * 10 * 64 * 8 * 2);  // single bf16

  hipMemsetAsync(zstart, 0, zbytes, stream);

  hist_kernel<<<(N_EDGES + 255) / 256, 256, 0, stream>>>(src, dst, deg_out, deg_in);
  norm_kernel<<<(N_NODES + 255) / 256, 256, 0, stream>>>(deg_out, deg_in, norm_out, norm_in);
  int nb = (N_NODES + 1023) / 1024;
  scan1_kernel<<<nb, 256, 0, stream>>>(deg_in, bsums);
  scan2_kernel<<<1, 64, 0, stream>>>(bsums, bofs, row_ptr, nb);
  scan3_kernel<<<nb, 256, 0, stream>>>(deg_in, bofs, row_ptr);
  csr_fill_kernel<<<(N_EDGES + 255) / 256, 256, 0, stream>>>(src, dst, row_ptr, fill, csr);
  wtrans_kernel<<<(5 * 5 * 10 * 64 * 8 + 255) / 256, 256, 0, stream>>>(W_emb, Ws, Wh);

  const size_t WHM = (size_t)5 * 10 * 64 * 8;      // Wh elems per matrix (25600)

  gemm_embed_kernel<<<GB, 512, 0, stream>>>(nodes_feat, Wh, b_emb, hbf);

  for (int l = 0; l < 4; l++) {
    float* st = stats + (size_t)l * ST_PART * 2 * DIM;
    agg_kernel<<<(N_NODES + 3) / 4, 256, 0, stream>>>(hbf, row_ptr, csr, norm_out, norm_in, xb);
    gemm_kernel<<<GB, 512, 0, stream>>>(xb, Wh + (size_t)(l + 1) * WHM, bs + l * DIM,
                                        snorm, tmpb, st);
    if (l < 3) {
      bn_kernel<<<(N_NODES * 20 + 255) / 256, 256, 0, stream>>>(
          tmpb, st, gammas + l * DIM, betas + l * DIM, hbf);
    } else {
      gsum_kernel<<<(N_NODES + 63) / 64, 192, 0, stream>>>(
          tmpb, st, gammas + l * DIM, betas + l * DIM, hbf, gids, hgp);
    }
  }

  mlp_kernel<<<N_GRAPHS, 256, 0, stream>>>(hgp, W1, b1, W2, b2, W3, b3, out);
}